// Round 1
// baseline (231.001 us; speedup 1.0000x reference)
//
#include <hip/hip_runtime.h>

#define KCODES 512
#define DDIM 64

// Pre-kernel: e_norm[k] = sum_d emb[k][d]^2  (512 floats into d_ws)
__global__ void vq_enorm_kernel(const float* __restrict__ emb, float* __restrict__ en) {
    int k = blockIdx.x * blockDim.x + threadIdx.x;
    if (k < KCODES) {
        float s = 0.f;
#pragma unroll
        for (int d = 0; d < DDIM; ++d) {
            float e = emb[k * DDIM + d];
            s = fmaf(e, e, s);
        }
        en[k] = s;
    }
}

// One thread per query row n (n = b*4096 + h*64 + w).
// z layout: [B, D, H, W] -> element (b, d, hw) at b*D*4096 + d*4096 + hw.
template <int KT>
__global__ __launch_bounds__(256) void vq_argmin_kernel(
    const float* __restrict__ z, const float* __restrict__ emb,
    const float* __restrict__ en, int* __restrict__ out, int nrows) {
    int n = blockIdx.x * blockDim.x + threadIdx.x;
    if (n >= nrows) return;
    int b = n >> 12;        // H*W = 4096
    int hw = n & 4095;
    const float* zp = z + (size_t)b * (DDIM * 4096) + hw;

    float zr[DDIM];
#pragma unroll
    for (int d = 0; d < DDIM; ++d) zr[d] = zp[(size_t)d * 4096];

    float zn = 0.f;
#pragma unroll
    for (int d = 0; d < DDIM; ++d) zn = fmaf(zr[d], zr[d], zn);

    float best = 3.4e38f;
    int bi = 0;
    for (int k0 = 0; k0 < KCODES; k0 += KT) {
        float acc[KT];
#pragma unroll
        for (int kk = 0; kk < KT; ++kk) acc[kk] = 0.f;
        const float* e0 = emb + k0 * DDIM;   // wave-uniform base
#pragma unroll
        for (int d = 0; d < DDIM; ++d) {
            float zd = zr[d];
#pragma unroll
            for (int kk = 0; kk < KT; ++kk)
                acc[kk] = fmaf(e0[kk * DDIM + d], zd, acc[kk]);
        }
#pragma unroll
        for (int kk = 0; kk < KT; ++kk) {
            float dist = zn + en[k0 + kk] - 2.f * acc[kk];
            if (dist < best) { best = dist; bi = k0 + kk; }  // strict < = first-occurrence tie-break
        }
    }
    out[n] = bi;
}

extern "C" void kernel_launch(void* const* d_in, const int* in_sizes, int n_in,
                              void* d_out, int out_size, void* d_ws, size_t ws_size,
                              hipStream_t stream) {
    const float* z   = (const float*)d_in[0];   // [32, 64, 64, 64] fp32
    const float* emb = (const float*)d_in[1];   // [512, 64] fp32
    int* out = (int*)d_out;                     // [32, 64, 64] int32
    float* en = (float*)d_ws;                   // 512 floats scratch

    vq_enorm_kernel<<<(KCODES + 255) / 256, 256, 0, stream>>>(emb, en);

    int nrows = out_size;                       // 131072
    int block = 256;
    int grid = (nrows + block - 1) / block;     // 512 blocks
    vq_argmin_kernel<8><<<grid, block, 0, stream>>>(z, emb, en, out, nrows);
}